// Round 5
// baseline (92.817 us; speedup 1.0000x reference)
//
#include <hip/hip_runtime.h>

#define BATCH 8
#define H 480
#define W 640
#define HW (H * W)
#define R 4
#define WP 648            // W + 2R (padded pitch); 648*4B = 162*16B (rows stay 16B-aligned)
#define HP 488            // H + 2R
#define PHW (WP * HP)

#define TS 32             // output tile of fused kernel
#define HALO 8            // up to 7 median passes + 1 for normals
#define LT 48             // TS + 2*HALO
#define CW 46             // per-pass compute width (LT-2)

__device__ __forceinline__ float exp2_fast(float x) {
#if __has_builtin(__builtin_amdgcn_exp2f)
    return __builtin_amdgcn_exp2f(x);
#else
    return exp2f(x);
#endif
}
__device__ __forceinline__ float rcp_fast(float x) {
#if __has_builtin(__builtin_amdgcn_rcpf)
    return __builtin_amdgcn_rcpf(x);
#else
    return 1.f / x;
#endif
}
__device__ __forceinline__ float rsq_fast(float x) {
#if __has_builtin(__builtin_amdgcn_rsqf)
    return __builtin_amdgcn_rsqf(x);
#else
    return rsqrtf(x);
#endif
}

// ---------------------------------------------------------------------------
// Kernel 0: zero-padded copy, one float4 per thread (rows of P are 162
// float4s: [0]=left pad, [1..160]=image, [161]=right pad).
// ---------------------------------------------------------------------------
__global__ __launch_bounds__(256) void pad_k(const float* __restrict__ din,
                                             float* __restrict__ P) {
    const int q = blockIdx.x * 256 + threadIdx.x;   // float4 index into P
    const int NQ = BATCH * PHW / 4;
    if (q >= NQ) return;
    const int per_b = PHW / 4;                      // 162*488
    const int b = q / per_b;
    const int rem = q - b * per_b;
    const int row = rem / 162;
    const int col4 = rem - row * 162;
    const int gy = row - R;
    float4 val = {0.f, 0.f, 0.f, 0.f};
    if ((unsigned)gy < (unsigned)H && col4 >= 1 && col4 <= 160) {
        val = *(const float4*)(din + (size_t)b * HW + (size_t)gy * W + (size_t)(col4 - 1) * 4);
    }
    *(float4*)(P + (size_t)q * 4) = val;
}

// ---------------------------------------------------------------------------
// Kernel 1: 9x9 bilateral, 4-px horizontal coarsening + ROW STREAMING.
// Per window row: 3 aligned float4 loads + 36 taps; only ~50 VGPR live, so
// __launch_bounds__(256,8) keeps 8 waves/SIMD resident (latency hiding +
// VALU/trans overlap across waves). The 5 per-row spatial constants are
// pinned into VGPRs via empty asm so v_fma takes (SGPR k_r, VGPR t2, VGPR sc)
// with no per-tap literal materialization.
// (nb>0) mask dropped: nb=0 => w<=3.7e-6, den>=1 => rel err <= 3e-4.
// ---------------------------------------------------------------------------
__global__ __launch_bounds__(256, 8) void bilateral_k(const float* __restrict__ P,
                                                      float* __restrict__ F) {
    const int tx = threadIdx.x;                       // 0..31
    const int ty = threadIdx.y;                       // 0..7
    const int x0 = blockIdx.x * 128 + tx * 4;         // first of 4 output cols
    const int y = blockIdx.y * 8 + ty;                // output row
    const int b = blockIdx.z;
    const float* p0 = P + (size_t)b * PHW + (size_t)y * WP + x0;

    const float k_r = -72.13475204444817f;            // -50 * log2(e)
    const float k_s = 1.4426950408889634f / 8.f;      // log2(e)/8

    // center values: window row 4, cols 4..7
    const float4 cc = *(const float4*)(p0 + 4 * WP + 4);
    float c[4] = {cc.x, cc.y, cc.z, cc.w};
    float num[4] = {0.f, 0.f, 0.f, 0.f};
    float den[4] = {0.f, 0.f, 0.f, 0.f};

#pragma unroll
    for (int j = 0; j < 9; ++j) {
        const float* pr = p0 + j * WP;
        const float4 q0 = *(const float4*)(pr);
        const float4 q1 = *(const float4*)(pr + 4);
        const float4 q2 = *(const float4*)(pr + 8);
        const float v[12] = {q0.x, q0.y, q0.z, q0.w,
                             q1.x, q1.y, q1.z, q1.w,
                             q2.x, q2.y, q2.z, q2.w};
        // 5 distinct spatial constants for this row (|dx| = 0..4), VGPR-pinned
        float scj[5];
#pragma unroll
        for (int a = 0; a < 5; ++a) {
            scj[a] = -(float)((j - 4) * (j - 4) + a * a) * k_s;
            asm volatile("" : "+v"(scj[a]));
        }
#pragma unroll
        for (int dx = -4; dx <= 4; ++dx) {
            const float sc = scj[dx < 0 ? -dx : dx];
#pragma unroll
            for (int k = 0; k < 4; ++k) {
                const float nb = v[4 + k + dx];
                const float t = c[k] - nb;
                const float w = exp2_fast(fmaf(t * t, k_r, sc));
                num[k] = fmaf(w, nb, num[k]);
                den[k] += w;
            }
        }
    }
    float* fo = F + (size_t)b * HW + (size_t)y * W + x0;
    float4 r;
    r.x = (c[0] > 0.f) ? num[0] * rcp_fast(den[0]) : 0.f;
    r.y = (c[1] > 0.f) ? num[1] * rcp_fast(den[1]) : 0.f;
    r.z = (c[2] > 0.f) ? num[2] * rcp_fast(den[2]) : 0.f;
    r.w = (c[3] > 0.f) ? num[3] * rcp_fast(den[3]) : 0.f;
    *(float4*)fo = r;
}

// ---------------------------------------------------------------------------
// Kernel 2: fused median-fill + normals, with early exit. median_fill only
// modifies ZERO cells, so once the normals' read region [7,41)^2 has no
// in-image zeros after pass k, remaining passes are bit-exact identities
// there -> break. Holes iid 0.5% => ~all tiles exit after 1 pass (7-pass
// fallback kept; exact region after k passes = [k,48-k) >= [7,41)).
// ---------------------------------------------------------------------------
__global__ __launch_bounds__(256) void fused_k(const float* __restrict__ F,
                                               const float* __restrict__ intr,
                                               float* __restrict__ out) {
    __shared__ float bufA[LT * LT];
    __shared__ float bufB[LT * LT];
    const int b = blockIdx.z;
    const int gx0 = blockIdx.x * TS - HALO;
    const int gy0 = blockIdx.y * TS - HALO;
    const float* img = F + (size_t)b * HW;
    const int tid = threadIdx.x;

    // load 48x48 with zero OOB
    for (int i = tid; i < LT * LT; i += 256) {
        const int r = i / LT, c = i - r * LT;
        const int gy = gy0 + r, gx = gx0 + c;
        const bool in = ((unsigned)gy < (unsigned)H) && ((unsigned)gx < (unsigned)W);
        bufA[i] = in ? img[(size_t)gy * W + gx] : 0.f;
    }
    __syncthreads();

    float* src = bufA;
    float* dst = bufB;
    for (int p = 0; p < 7; ++p) {
        int flag = 0;
        for (int i = tid; i < CW * CW; i += 256) {
            const int r = i / CW + 1;
            const int c = i - (r - 1) * CW + 1;
            const int gy = gy0 + r, gx = gx0 + c;
            const bool inimg = ((unsigned)gy < (unsigned)H) && ((unsigned)gx < (unsigned)W);
            const float cc = src[r * LT + c];
            float o = 0.f;
            if (inimg) {
                if (cc != 0.f) {
                    o = cc;  // fast path (>99% of cells)
                } else {
                    float e[9];
                    int cnt = 0;
#pragma unroll
                    for (int dy = -1; dy <= 1; ++dy) {
#pragma unroll
                        for (int dx = -1; dx <= 1; ++dx) {
                            const float nb = src[(r + dy) * LT + (c + dx)];
                            const bool vv = nb > 0.f;
                            cnt += vv ? 1 : 0;
                            e[(dy + 1) * 3 + (dx + 1)] = vv ? nb : 1e10f;
                        }
                    }
#pragma unroll
                    for (int ii = 0; ii < 8; ++ii) {
#pragma unroll
                        for (int jj = 0; jj < 8 - ii; ++jj) {
                            const float a = e[jj], bb = e[jj + 1];
                            e[jj] = fminf(a, bb);
                            e[jj + 1] = fmaxf(a, bb);
                        }
                    }
                    o = (cnt > 0) ? e[(cnt - 1) >> 1] : 0.f;
                }
                if (o == 0.f && (unsigned)(r - 7) < 34u && (unsigned)(c - 7) < 34u)
                    flag = 1;
            }
            dst[r * LT + c] = o;
        }
        const int any = __syncthreads_or(flag);
        float* t = src; src = dst; dst = t;
        if (!any) break;
    }
    // src holds the converged (or 7-pass) result; exact on [7,41)^2

    const float fx = intr[b * 4 + 0];
    const float fy = intr[b * 4 + 1];
    const float cx = intr[b * 4 + 2];
    const float cy = intr[b * 4 + 3];
    const float invfx = rcp_fast(fx);
    const float invfy = rcp_fast(fy);

    for (int i = tid; i < TS * TS; i += 256) {
        const int oy = i >> 5, ox = i & 31;
        const int gy = gy0 + HALO + oy;
        const int gx = gx0 + HALO + ox;
        const size_t o = (size_t)b * 3 * HW + (size_t)gy * W + gx;
        if (gx == 0 || gy == 0 || gx == W - 1 || gy == H - 1) {
            out[o] = 0.f; out[o + HW] = 0.f; out[o + 2 * HW] = 0.f;
            continue;
        }
        const int r = HALO + oy, c = HALO + ox;
        const int offy[5] = {0, 0, -1, 1, 0};   // l, r, u, d, center
        const int offx[5] = {-1, 1, 0, 0, 0};
        float X[5], Y[5], Z[5];
#pragma unroll
        for (int k = 0; k < 5; ++k) {
            const float dv = src[(r + offy[k]) * LT + (c + offx[k])];
            const bool v = (dv >= 0.1f) && (dv <= 6.0f);
            const float dvv = v ? dv : 0.f;
            X[k] = ((float)(gx + offx[k]) - cx) * dvv * invfx;
            Y[k] = ((float)(gy + offy[k]) - cy) * dvv * invfy;
            Z[k] = dvv;
        }
        const float ax = X[3] - X[2], ay = Y[3] - Y[2], az = Z[3] - Z[2];  // dy_vec
        const float bx = X[1] - X[0], by = Y[1] - Y[0], bz = Z[1] - Z[0];  // dx_vec
        const float nx = ay * bz - az * by;
        const float ny = az * bx - ax * bz;
        const float nz = ax * by - ay * bx;
        const bool z_ok = (Z[0] > 0.f) && (Z[1] > 0.f) && (Z[2] > 0.f) && (Z[3] > 0.f) && (Z[4] > 0.f);
        const float s = nx * nx + ny * ny + nz * nz;
        const bool ok = (s > 1e-16f) && z_ok;
        const float inv = ok ? rsq_fast(s) : 0.f;
        out[o] = nx * inv;
        out[o + HW] = ny * inv;
        out[o + 2 * HW] = nz * inv;
    }
}

// ---------------------------------------------------------------------------
// Pipeline: pad (float4) -> bilateral (row-streamed, 8 waves/SIMD) ->
// fused(median w/ early exit + normals). ws: P (10.12 MB) + F (9.83 MB).
// ---------------------------------------------------------------------------
extern "C" void kernel_launch(void* const* d_in, const int* in_sizes, int n_in,
                              void* d_out, int out_size, void* d_ws, size_t ws_size,
                              hipStream_t stream) {
    const float* depth = (const float*)d_in[0];
    const float* intr = (const float*)d_in[1];
    float* out = (float*)d_out;
    float* P = (float*)d_ws;
    float* F = P + (size_t)BATCH * PHW;

    const int NQ = BATCH * PHW / 4;
    pad_k<<<(NQ + 255) / 256, 256, 0, stream>>>(depth, P);

    dim3 bblk(32, 8, 1);
    dim3 bgrd(W / 128, H / 8, BATCH);
    bilateral_k<<<bgrd, bblk, 0, stream>>>(P, F);

    dim3 fgrd(W / TS, H / TS, BATCH);
    fused_k<<<fgrd, 256, 0, stream>>>(F, intr, out);
}

// Round 6
// 75.706 us; speedup vs baseline: 1.2260x; 1.2260x over previous
//
#include <hip/hip_runtime.h>

#define BATCH 8
#define H 480
#define W 640
#define HW (H * W)
#define R 4
#define WP 648            // W + 2R (padded pitch); 648*4B = 162*16B (rows stay 16B-aligned)
#define HP 488            // H + 2R
#define PHW (WP * HP)

#define TS 32             // output tile of fused kernel
#define HALO 8            // up to 7 median passes + 1 for normals
#define LT 48             // TS + 2*HALO
#define CW 46             // per-pass compute width (LT-2)

__device__ __forceinline__ float exp2_fast(float x) {
#if __has_builtin(__builtin_amdgcn_exp2f)
    return __builtin_amdgcn_exp2f(x);
#else
    return exp2f(x);
#endif
}
__device__ __forceinline__ float rcp_fast(float x) {
#if __has_builtin(__builtin_amdgcn_rcpf)
    return __builtin_amdgcn_rcpf(x);
#else
    return 1.f / x;
#endif
}
__device__ __forceinline__ float rsq_fast(float x) {
#if __has_builtin(__builtin_amdgcn_rsqf)
    return __builtin_amdgcn_rsqf(x);
#else
    return rsqrtf(x);
#endif
}

// ---------------------------------------------------------------------------
// Kernel 0: zero-padded copy, one float4 per thread (rows of P are 162
// float4s: [0]=left pad, [1..160]=image, [161]=right pad).
// ---------------------------------------------------------------------------
__global__ __launch_bounds__(256) void pad_k(const float* __restrict__ din,
                                             float* __restrict__ P) {
    const int q = blockIdx.x * 256 + threadIdx.x;   // float4 index into P
    const int NQ = BATCH * PHW / 4;
    if (q >= NQ) return;
    const int per_b = PHW / 4;                      // 162*488
    const int b = q / per_b;
    const int rem = q - b * per_b;
    const int row = rem / 162;
    const int col4 = rem - row * 162;
    const int gy = row - R;
    float4 val = {0.f, 0.f, 0.f, 0.f};
    if ((unsigned)gy < (unsigned)H && col4 >= 1 && col4 <= 160) {
        val = *(const float4*)(din + (size_t)b * HW + (size_t)gy * W + (size_t)(col4 - 1) * 4);
    }
    *(float4*)(P + (size_t)q * 4) = val;
}

// ---------------------------------------------------------------------------
// Kernel 1: 9x9 bilateral, 4-px horizontal coarsening, STREAMING row loop
// (#pragma unroll 1) so the live set stays ~45 VGPR -> 8 waves/SIMD resident
// with NO launch_bounds cap (R4's forced cap spilled to scratch: 151 MB
// writes). Per row: 3 aligned dwordx4 loads off one incremented base
// (offset: imm), 5 VGPR-pinned spatial constants, 36 taps of
// {sub, mul, fma, exp2, fmac, add}. (nb>0) mask dropped: nb=0 => w<=3.7e-6,
// den>=1 => rel err <= 3e-4 << 0.02 threshold.
// ---------------------------------------------------------------------------
__global__ void bilateral_k(const float* __restrict__ P,
                            float* __restrict__ F) {
    const int tx = threadIdx.x;                       // 0..15
    const int ty = threadIdx.y;                       // 0..7
    const int x0 = blockIdx.x * 64 + tx * 4;          // first of 4 output cols
    const int y = blockIdx.y * 8 + ty;                // output row
    const int b = blockIdx.z;
    const float* p0 = P + (size_t)b * PHW + (size_t)y * WP + x0;

    const float k_r = -72.13475204444817f;            // -50 * log2(e)
    const float k_s = 1.4426950408889634f / 8.f;      // log2(e)/8

    // center values: window row 4, cols 4..7 (one extra aligned load up-front)
    const float4 cc = *(const float4*)(p0 + 4 * WP + 4);
    float c[4] = {cc.x, cc.y, cc.z, cc.w};
    float num[4] = {0.f, 0.f, 0.f, 0.f};
    float den[4] = {0.f, 0.f, 0.f, 0.f};

    const float* pr = p0;
#pragma unroll 1
    for (int j = 0; j < 9; ++j) {
        const float4 q0 = *(const float4*)(pr);
        const float4 q1 = *(const float4*)(pr + 4);
        const float4 q2 = *(const float4*)(pr + 8);
        pr += WP;
        const float v[12] = {q0.x, q0.y, q0.z, q0.w,
                             q1.x, q1.y, q1.z, q1.w,
                             q2.x, q2.y, q2.z, q2.w};
        // 5 distinct spatial constants for this row (|dx| = 0..4), VGPR-pinned
        // so v_fma(t2, s[k_r], v[sc]) needs no per-tap literal.
        const float fj = (float)((j - 4) * (j - 4));
        float scj[5];
#pragma unroll
        for (int a = 0; a < 5; ++a) {
            scj[a] = -(fj + (float)(a * a)) * k_s;
            asm("" : "+v"(scj[a]));
        }
#pragma unroll
        for (int dx = -4; dx <= 4; ++dx) {
            const float sc = scj[dx < 0 ? -dx : dx];
#pragma unroll
            for (int k = 0; k < 4; ++k) {
                const float nb = v[4 + k + dx];
                const float t = c[k] - nb;
                const float w = exp2_fast(fmaf(t * t, k_r, sc));
                num[k] = fmaf(w, nb, num[k]);
                den[k] += w;
            }
        }
    }
    float* fo = F + (size_t)b * HW + (size_t)y * W + x0;
    float4 r;
    r.x = (c[0] > 0.f) ? num[0] * rcp_fast(den[0]) : 0.f;
    r.y = (c[1] > 0.f) ? num[1] * rcp_fast(den[1]) : 0.f;
    r.z = (c[2] > 0.f) ? num[2] * rcp_fast(den[2]) : 0.f;
    r.w = (c[3] > 0.f) ? num[3] * rcp_fast(den[3]) : 0.f;
    *(float4*)fo = r;
}

// ---------------------------------------------------------------------------
// Kernel 2: fused median-fill + normals, with early exit. median_fill only
// modifies ZERO cells, so once the normals' read region [7,41)^2 has no
// in-image zeros after pass k, remaining passes are bit-exact identities
// there -> break. Holes iid 0.5% => ~all tiles exit after 1 pass (7-pass
// fallback kept; exact region after k passes = [k,48-k) >= [7,41)).
// ---------------------------------------------------------------------------
__global__ __launch_bounds__(256) void fused_k(const float* __restrict__ F,
                                               const float* __restrict__ intr,
                                               float* __restrict__ out) {
    __shared__ float bufA[LT * LT];
    __shared__ float bufB[LT * LT];
    const int b = blockIdx.z;
    const int gx0 = blockIdx.x * TS - HALO;
    const int gy0 = blockIdx.y * TS - HALO;
    const float* img = F + (size_t)b * HW;
    const int tid = threadIdx.x;

    // load 48x48 with zero OOB
    for (int i = tid; i < LT * LT; i += 256) {
        const int r = i / LT, c = i - r * LT;
        const int gy = gy0 + r, gx = gx0 + c;
        const bool in = ((unsigned)gy < (unsigned)H) && ((unsigned)gx < (unsigned)W);
        bufA[i] = in ? img[(size_t)gy * W + gx] : 0.f;
    }
    __syncthreads();

    float* src = bufA;
    float* dst = bufB;
    for (int p = 0; p < 7; ++p) {
        int flag = 0;
        for (int i = tid; i < CW * CW; i += 256) {
            const int r = i / CW + 1;
            const int c = i - (r - 1) * CW + 1;
            const int gy = gy0 + r, gx = gx0 + c;
            const bool inimg = ((unsigned)gy < (unsigned)H) && ((unsigned)gx < (unsigned)W);
            const float cc = src[r * LT + c];
            float o = 0.f;
            if (inimg) {
                if (cc != 0.f) {
                    o = cc;  // fast path (>99% of cells)
                } else {
                    float e[9];
                    int cnt = 0;
#pragma unroll
                    for (int dy = -1; dy <= 1; ++dy) {
#pragma unroll
                        for (int dx = -1; dx <= 1; ++dx) {
                            const float nb = src[(r + dy) * LT + (c + dx)];
                            const bool vv = nb > 0.f;
                            cnt += vv ? 1 : 0;
                            e[(dy + 1) * 3 + (dx + 1)] = vv ? nb : 1e10f;
                        }
                    }
#pragma unroll
                    for (int ii = 0; ii < 8; ++ii) {
#pragma unroll
                        for (int jj = 0; jj < 8 - ii; ++jj) {
                            const float a = e[jj], bb = e[jj + 1];
                            e[jj] = fminf(a, bb);
                            e[jj + 1] = fmaxf(a, bb);
                        }
                    }
                    o = (cnt > 0) ? e[(cnt - 1) >> 1] : 0.f;
                }
                if (o == 0.f && (unsigned)(r - 7) < 34u && (unsigned)(c - 7) < 34u)
                    flag = 1;
            }
            dst[r * LT + c] = o;
        }
        const int any = __syncthreads_or(flag);
        float* t = src; src = dst; dst = t;
        if (!any) break;
    }
    // src holds the converged (or 7-pass) result; exact on [7,41)^2

    const float fx = intr[b * 4 + 0];
    const float fy = intr[b * 4 + 1];
    const float cx = intr[b * 4 + 2];
    const float cy = intr[b * 4 + 3];
    const float invfx = rcp_fast(fx);
    const float invfy = rcp_fast(fy);

    for (int i = tid; i < TS * TS; i += 256) {
        const int oy = i >> 5, ox = i & 31;
        const int gy = gy0 + HALO + oy;
        const int gx = gx0 + HALO + ox;
        const size_t o = (size_t)b * 3 * HW + (size_t)gy * W + gx;
        if (gx == 0 || gy == 0 || gx == W - 1 || gy == H - 1) {
            out[o] = 0.f; out[o + HW] = 0.f; out[o + 2 * HW] = 0.f;
            continue;
        }
        const int r = HALO + oy, c = HALO + ox;
        const int offy[5] = {0, 0, -1, 1, 0};   // l, r, u, d, center
        const int offx[5] = {-1, 1, 0, 0, 0};
        float X[5], Y[5], Z[5];
#pragma unroll
        for (int k = 0; k < 5; ++k) {
            const float dv = src[(r + offy[k]) * LT + (c + offx[k])];
            const bool v = (dv >= 0.1f) && (dv <= 6.0f);
            const float dvv = v ? dv : 0.f;
            X[k] = ((float)(gx + offx[k]) - cx) * dvv * invfx;
            Y[k] = ((float)(gy + offy[k]) - cy) * dvv * invfy;
            Z[k] = dvv;
        }
        const float ax = X[3] - X[2], ay = Y[3] - Y[2], az = Z[3] - Z[2];  // dy_vec
        const float bx = X[1] - X[0], by = Y[1] - Y[0], bz = Z[1] - Z[0];  // dx_vec
        const float nx = ay * bz - az * by;
        const float ny = az * bx - ax * bz;
        const float nz = ax * by - ay * bx;
        const bool z_ok = (Z[0] > 0.f) && (Z[1] > 0.f) && (Z[2] > 0.f) && (Z[3] > 0.f) && (Z[4] > 0.f);
        const float s = nx * nx + ny * ny + nz * nz;
        const bool ok = (s > 1e-16f) && z_ok;
        const float inv = ok ? rsq_fast(s) : 0.f;
        out[o] = nx * inv;
        out[o + HW] = ny * inv;
        out[o + 2 * HW] = nz * inv;
    }
}

// ---------------------------------------------------------------------------
// Pipeline: pad (float4) -> bilateral (streamed rows, natural ~45 VGPR,
// 128-thread blocks, 4800 blocks) -> fused(median early-exit + normals).
// ws: P (10.12 MB) + F (9.83 MB).
// ---------------------------------------------------------------------------
extern "C" void kernel_launch(void* const* d_in, const int* in_sizes, int n_in,
                              void* d_out, int out_size, void* d_ws, size_t ws_size,
                              hipStream_t stream) {
    const float* depth = (const float*)d_in[0];
    const float* intr = (const float*)d_in[1];
    float* out = (float*)d_out;
    float* P = (float*)d_ws;
    float* F = P + (size_t)BATCH * PHW;

    const int NQ = BATCH * PHW / 4;
    pad_k<<<(NQ + 255) / 256, 256, 0, stream>>>(depth, P);

    dim3 bblk(16, 8, 1);                 // 128 threads: 64 cols x 8 rows
    dim3 bgrd(W / 64, H / 8, BATCH);     // 10 x 60 x 8 = 4800 blocks
    bilateral_k<<<bgrd, bblk, 0, stream>>>(P, F);

    dim3 fgrd(W / TS, H / TS, BATCH);
    fused_k<<<fgrd, 256, 0, stream>>>(F, intr, out);
}

// Round 7
// 75.394 us; speedup vs baseline: 1.2311x; 1.0041x over previous
//
#include <hip/hip_runtime.h>

#define BATCH 8
#define H 480
#define W 640
#define HW (H * W)
#define R 4
#define WP 648            // W + 2R (padded pitch); 648*4B = 162*16B (rows stay 16B-aligned)
#define HP 488            // H + 2R
#define PHW (WP * HP)

#define TS 32             // output tile of fused kernel
#define HALO 8            // up to 7 median passes + 1 for normals
#define LT 48             // TS + 2*HALO
#define CW 46             // per-pass compute width (LT-2)

__device__ __forceinline__ float exp2_fast(float x) {
#if __has_builtin(__builtin_amdgcn_exp2f)
    return __builtin_amdgcn_exp2f(x);
#else
    return exp2f(x);
#endif
}
__device__ __forceinline__ float rcp_fast(float x) {
#if __has_builtin(__builtin_amdgcn_rcpf)
    return __builtin_amdgcn_rcpf(x);
#else
    return 1.f / x;
#endif
}
__device__ __forceinline__ float rsq_fast(float x) {
#if __has_builtin(__builtin_amdgcn_rsqf)
    return __builtin_amdgcn_rsqf(x);
#else
    return rsqrtf(x);
#endif
}

// ---------------------------------------------------------------------------
// Kernel 0: zero-padded copy, one float4 per thread (rows of P are 162
// float4s: [0]=left pad, [1..160]=image, [161]=right pad).
// ---------------------------------------------------------------------------
__global__ __launch_bounds__(256) void pad_k(const float* __restrict__ din,
                                             float* __restrict__ P) {
    const int q = blockIdx.x * 256 + threadIdx.x;   // float4 index into P
    const int NQ = BATCH * PHW / 4;
    if (q >= NQ) return;
    const int per_b = PHW / 4;                      // 162*488
    const int b = q / per_b;
    const int rem = q - b * per_b;
    const int row = rem / 162;
    const int col4 = rem - row * 162;
    const int gy = row - R;
    float4 val = {0.f, 0.f, 0.f, 0.f};
    if ((unsigned)gy < (unsigned)H && col4 >= 1 && col4 <= 160) {
        val = *(const float4*)(din + (size_t)b * HW + (size_t)gy * W + (size_t)(col4 - 1) * 4);
    }
    *(float4*)(P + (size_t)q * 4) = val;
}

// ---------------------------------------------------------------------------
// Kernel 1: 9x9 bilateral, 4-px horizontal coarsening, SOFTWARE-PIPELINED
// row loop: loads for row j+1 are issued BEFORE computing row j (explicit
// double buffer, unroll 1 so the compiler can't burst-hoist all rows like
// R3's 128-VGPR version). The vmcnt wait for row j+1 lands after ~648 cyc
// of row-j compute, hiding the ~200-400 cyc L2 latency that caused R2/R3/
// R5's invariant 35% stall. Last iter re-reads row y (pointer select) to
// stay inside the padded image. (nb>0) mask dropped: nb=0 => w<=3.7e-6,
// den>=1 => rel err <= 3e-4 << 0.02 threshold.
// ---------------------------------------------------------------------------
__global__ void bilateral_k(const float* __restrict__ P,
                            float* __restrict__ F) {
    const int tx = threadIdx.x;                       // 0..15
    const int ty = threadIdx.y;                       // 0..7
    const int x0 = blockIdx.x * 64 + tx * 4;          // first of 4 output cols
    const int y = blockIdx.y * 8 + ty;                // output row
    const int b = blockIdx.z;
    const float* p0 = P + (size_t)b * PHW + (size_t)y * WP + x0;

    const float k_r = -72.13475204444817f;            // -50 * log2(e)
    const float k_s = 1.4426950408889634f / 8.f;      // log2(e)/8

    // center values: window row 4, cols 4..7
    const float4 cc = *(const float4*)(p0 + 4 * WP + 4);
    float c[4] = {cc.x, cc.y, cc.z, cc.w};
    float num[4] = {0.f, 0.f, 0.f, 0.f};
    float den[4] = {0.f, 0.f, 0.f, 0.f};

    // prefetch row 0
    float4 a0 = *(const float4*)(p0);
    float4 a1 = *(const float4*)(p0 + 4);
    float4 a2 = *(const float4*)(p0 + 8);
    const float* pr = p0 + WP;                        // next row to load

#pragma unroll 1
    for (int j = 0; j < 9; ++j) {
        // issue loads for row j+1 (j==8: harmlessly re-read row 0 area via p0
        // to avoid reading padded row y+9 which can be out of the image)
        const float* pp = (j < 8) ? pr : p0;
        const float4 b0 = *(const float4*)(pp);
        const float4 b1 = *(const float4*)(pp + 4);
        const float4 b2 = *(const float4*)(pp + 8);
        pr += WP;

        // compute on previously-loaded row j
        const float v[12] = {a0.x, a0.y, a0.z, a0.w,
                             a1.x, a1.y, a1.z, a1.w,
                             a2.x, a2.y, a2.z, a2.w};
        const float fj = (float)((j - 4) * (j - 4));
        float scj[5];
#pragma unroll
        for (int a = 0; a < 5; ++a) {
            scj[a] = -(fj + (float)(a * a)) * k_s;
            asm("" : "+v"(scj[a]));
        }
#pragma unroll
        for (int dx = -4; dx <= 4; ++dx) {
            const float sc = scj[dx < 0 ? -dx : dx];
#pragma unroll
            for (int k = 0; k < 4; ++k) {
                const float nb = v[4 + k + dx];
                const float t = c[k] - nb;
                const float w = exp2_fast(fmaf(t * t, k_r, sc));
                num[k] = fmaf(w, nb, num[k]);
                den[k] += w;
            }
        }
        // rotate buffers (waitcnt for b-loads lands here, after the compute)
        a0 = b0; a1 = b1; a2 = b2;
    }
    float* fo = F + (size_t)b * HW + (size_t)y * W + x0;
    float4 r;
    r.x = (c[0] > 0.f) ? num[0] * rcp_fast(den[0]) : 0.f;
    r.y = (c[1] > 0.f) ? num[1] * rcp_fast(den[1]) : 0.f;
    r.z = (c[2] > 0.f) ? num[2] * rcp_fast(den[2]) : 0.f;
    r.w = (c[3] > 0.f) ? num[3] * rcp_fast(den[3]) : 0.f;
    *(float4*)fo = r;
}

// ---------------------------------------------------------------------------
// Kernel 2: fused median-fill + normals, with early exit. median_fill only
// modifies ZERO cells, so once the normals' read region [7,41)^2 has no
// in-image zeros after pass k, remaining passes are bit-exact identities
// there -> break. Holes iid 0.5% => ~all tiles exit after 1 pass (7-pass
// fallback kept; exact region after k passes = [k,48-k) >= [7,41)).
// ---------------------------------------------------------------------------
__global__ __launch_bounds__(256) void fused_k(const float* __restrict__ F,
                                               const float* __restrict__ intr,
                                               float* __restrict__ out) {
    __shared__ float bufA[LT * LT];
    __shared__ float bufB[LT * LT];
    const int b = blockIdx.z;
    const int gx0 = blockIdx.x * TS - HALO;
    const int gy0 = blockIdx.y * TS - HALO;
    const float* img = F + (size_t)b * HW;
    const int tid = threadIdx.x;

    // load 48x48 with zero OOB
    for (int i = tid; i < LT * LT; i += 256) {
        const int r = i / LT, c = i - r * LT;
        const int gy = gy0 + r, gx = gx0 + c;
        const bool in = ((unsigned)gy < (unsigned)H) && ((unsigned)gx < (unsigned)W);
        bufA[i] = in ? img[(size_t)gy * W + gx] : 0.f;
    }
    __syncthreads();

    float* src = bufA;
    float* dst = bufB;
    for (int p = 0; p < 7; ++p) {
        int flag = 0;
        for (int i = tid; i < CW * CW; i += 256) {
            const int r = i / CW + 1;
            const int c = i - (r - 1) * CW + 1;
            const int gy = gy0 + r, gx = gx0 + c;
            const bool inimg = ((unsigned)gy < (unsigned)H) && ((unsigned)gx < (unsigned)W);
            const float cc = src[r * LT + c];
            float o = 0.f;
            if (inimg) {
                if (cc != 0.f) {
                    o = cc;  // fast path (>99% of cells)
                } else {
                    float e[9];
                    int cnt = 0;
#pragma unroll
                    for (int dy = -1; dy <= 1; ++dy) {
#pragma unroll
                        for (int dx = -1; dx <= 1; ++dx) {
                            const float nb = src[(r + dy) * LT + (c + dx)];
                            const bool vv = nb > 0.f;
                            cnt += vv ? 1 : 0;
                            e[(dy + 1) * 3 + (dx + 1)] = vv ? nb : 1e10f;
                        }
                    }
#pragma unroll
                    for (int ii = 0; ii < 8; ++ii) {
#pragma unroll
                        for (int jj = 0; jj < 8 - ii; ++jj) {
                            const float a = e[jj], bb = e[jj + 1];
                            e[jj] = fminf(a, bb);
                            e[jj + 1] = fmaxf(a, bb);
                        }
                    }
                    o = (cnt > 0) ? e[(cnt - 1) >> 1] : 0.f;
                }
                if (o == 0.f && (unsigned)(r - 7) < 34u && (unsigned)(c - 7) < 34u)
                    flag = 1;
            }
            dst[r * LT + c] = o;
        }
        const int any = __syncthreads_or(flag);
        float* t = src; src = dst; dst = t;
        if (!any) break;
    }
    // src holds the converged (or 7-pass) result; exact on [7,41)^2

    const float fx = intr[b * 4 + 0];
    const float fy = intr[b * 4 + 1];
    const float cx = intr[b * 4 + 2];
    const float cy = intr[b * 4 + 3];
    const float invfx = rcp_fast(fx);
    const float invfy = rcp_fast(fy);

    for (int i = tid; i < TS * TS; i += 256) {
        const int oy = i >> 5, ox = i & 31;
        const int gy = gy0 + HALO + oy;
        const int gx = gx0 + HALO + ox;
        const size_t o = (size_t)b * 3 * HW + (size_t)gy * W + gx;
        if (gx == 0 || gy == 0 || gx == W - 1 || gy == H - 1) {
            out[o] = 0.f; out[o + HW] = 0.f; out[o + 2 * HW] = 0.f;
            continue;
        }
        const int r = HALO + oy, c = HALO + ox;
        const int offy[5] = {0, 0, -1, 1, 0};   // l, r, u, d, center
        const int offx[5] = {-1, 1, 0, 0, 0};
        float X[5], Y[5], Z[5];
#pragma unroll
        for (int k = 0; k < 5; ++k) {
            const float dv = src[(r + offy[k]) * LT + (c + offx[k])];
            const bool v = (dv >= 0.1f) && (dv <= 6.0f);
            const float dvv = v ? dv : 0.f;
            X[k] = ((float)(gx + offx[k]) - cx) * dvv * invfx;
            Y[k] = ((float)(gy + offy[k]) - cy) * dvv * invfy;
            Z[k] = dvv;
        }
        const float ax = X[3] - X[2], ay = Y[3] - Y[2], az = Z[3] - Z[2];  // dy_vec
        const float bx = X[1] - X[0], by = Y[1] - Y[0], bz = Z[1] - Z[0];  // dx_vec
        const float nx = ay * bz - az * by;
        const float ny = az * bx - ax * bz;
        const float nz = ax * by - ay * bx;
        const bool z_ok = (Z[0] > 0.f) && (Z[1] > 0.f) && (Z[2] > 0.f) && (Z[3] > 0.f) && (Z[4] > 0.f);
        const float s = nx * nx + ny * ny + nz * nz;
        const bool ok = (s > 1e-16f) && z_ok;
        const float inv = ok ? rsq_fast(s) : 0.f;
        out[o] = nx * inv;
        out[o + HW] = ny * inv;
        out[o + 2 * HW] = nz * inv;
    }
}

// ---------------------------------------------------------------------------
// Pipeline: pad (float4) -> bilateral (software-pipelined rows) ->
// fused(median early-exit + normals). ws: P (10.12 MB) + F (9.83 MB).
// ---------------------------------------------------------------------------
extern "C" void kernel_launch(void* const* d_in, const int* in_sizes, int n_in,
                              void* d_out, int out_size, void* d_ws, size_t ws_size,
                              hipStream_t stream) {
    const float* depth = (const float*)d_in[0];
    const float* intr = (const float*)d_in[1];
    float* out = (float*)d_out;
    float* P = (float*)d_ws;
    float* F = P + (size_t)BATCH * PHW;

    const int NQ = BATCH * PHW / 4;
    pad_k<<<(NQ + 255) / 256, 256, 0, stream>>>(depth, P);

    dim3 bblk(16, 8, 1);                 // 128 threads: 64 cols x 8 rows
    dim3 bgrd(W / 64, H / 8, BATCH);     // 10 x 60 x 8 = 4800 blocks
    bilateral_k<<<bgrd, bblk, 0, stream>>>(P, F);

    dim3 fgrd(W / TS, H / TS, BATCH);
    fused_k<<<fgrd, 256, 0, stream>>>(F, intr, out);
}